// Round 20
// baseline (116.514 us; speedup 1.0000x reference)
//
#include <hip/hip_runtime.h>

typedef __attribute__((ext_vector_type(8))) short bf16x8;
typedef __attribute__((ext_vector_type(4))) float f32x4;

constexpr int Bb = 32, Cc = 256, Nn = 1024;
constexpr float EPSf = 1e-5f;
// scale 256^-0.5 with log2(e) folded in: softmax uses exp2 on pre-scaled scores
constexpr float QSCALE = 0.0625f * 1.44269504088896f;

__device__ __forceinline__ unsigned short f2bf(float f) {
  union { float f; unsigned u; } v; v.f = f;
  unsigned r = v.u + 0x7fffu + ((v.u >> 16) & 1u);
  return (unsigned short)(r >> 16);
}

__device__ __forceinline__ bf16x8 ldb8(const unsigned short* p) {
  return *reinterpret_cast<const bf16x8*>(p);
}

__device__ __forceinline__ void gload16(const void* g, void* l) {
  __builtin_amdgcn_global_load_lds((const __attribute__((address_space(1))) void*)g,
                                   (__attribute__((address_space(3))) void*)l, 16, 0, 0);
}

__device__ __forceinline__ float fexp2(float x) {
  float r;
  asm("v_exp_f32 %0, %1" : "=v"(r) : "v"(x));
  return r;
}

// ---------------- fused groupnorm (+ weight cvt piggybacked on spare blocks) ----------------
__global__ void __launch_bounds__(256) gn_cvt_kernel(
    const float* __restrict__ x, const float* __restrict__ gw, const float* __restrict__ gb,
    unsigned short* __restrict__ hT,
    const float* __restrict__ wq, const float* __restrict__ wk,
    const float* __restrict__ wv, const float* __restrict__ wo,
    unsigned short* __restrict__ wbf) {
  __shared__ float xs[8192];
  __shared__ float red[8];
  if (blockIdx.x >= 1024) {
    int i = (blockIdx.x - 1024) * 256 + threadIdx.x;
    wbf[i]          = f2bf(wq[i]);
    wbf[65536 + i]  = f2bf(wk[i]);
    wbf[131072 + i] = f2bf(wv[i]);
    wbf[196608 + i] = f2bf(wo[i]);
    return;
  }
  int b = blockIdx.x >> 5, g = blockIdx.x & 31;
  const float4* xg = (const float4*)(x + ((size_t)b * 32 + g) * 8192);
  float s = 0.f, ss = 0.f;
  for (int i = threadIdx.x; i < 2048; i += 256) {
    float4 v = xg[i];
    ((float4*)xs)[i] = v;
    s += v.x + v.y + v.z + v.w;
    ss += v.x * v.x + v.y * v.y + v.z * v.z + v.w * v.w;
  }
  for (int o = 1; o < 64; o <<= 1) { s += __shfl_xor(s, o, 64); ss += __shfl_xor(ss, o, 64); }
  int wid = threadIdx.x >> 6;
  if ((threadIdx.x & 63) == 0) { red[wid] = s; red[4 + wid] = ss; }
  __syncthreads();
  float S  = red[0] + red[1] + red[2] + red[3];
  float SS = red[4] + red[5] + red[6] + red[7];
  float mean = S * (1.f / 8192.f);
  float rstd = rsqrtf(SS * (1.f / 8192.f) - mean * mean + EPSf);
  float w8[8], b8[8];
#pragma unroll
  for (int c = 0; c < 8; ++c) {
    w8[c] = gw[g * 8 + c] * rstd;
    b8[c] = gb[g * 8 + c] - mean * w8[c];
  }
  unsigned short* ob = hT + (size_t)b * Nn * Cc + g * 8;
#pragma unroll
  for (int k = 0; k < 4; ++k) {
    int n = threadIdx.x + 256 * k;
    union { unsigned short u[8]; uint4 v; } pk;
#pragma unroll
    for (int c = 0; c < 8; ++c) pk.u[c] = f2bf(xs[c * 1024 + n] * w8[c] + b8[c]);
    *reinterpret_cast<uint4*>(ob + (size_t)n * Cc) = pk.v;
  }
}

// ---------------- Q, K and V projections: 64-row h-tile (32KB LDS), 3 GEMMs ----------------
// grid (32, BG): i2>>1 = 64-row n-tile, i2&1 = 128-ch half. 32KB LDS -> 4 blocks/CU.
// Output layouts (byte-identical to R18):
// Q8/K8: byte(n,ch) = (n>>4)*4096 + (ch>>5)*512 + ((n&15)+16*((ch>>3)&3))*8 + (ch&7)
// V8:    byte(ch,m) = (m>>5)*8192 + (ch>>4)*512 + ((ch&15)+16*((m&31)>>3))*8 + (m&7)
// Q8 has bq added and QSCALE folded before fp8 quantization.
__global__ void __launch_bounds__(256, 4) qkv_gemm_kernel(
    const unsigned short* __restrict__ hT, const unsigned short* __restrict__ wbf,
    unsigned char* __restrict__ Q8g, unsigned char* __restrict__ K8g,
    unsigned char* __restrict__ V8g,
    const float* __restrict__ bq, const float* __restrict__ bk, const float* __restrict__ bv) {
  int bz = blockIdx.y;
  const unsigned short* h = hT + (size_t)bz * Nn * Cc;
  int i2 = blockIdx.x;
  int hbase = (i2 >> 1) * 64;    // n-tile (64 rows)
  int chh = (i2 & 1) * 128;      // ch half

  __shared__ alignas(16) char hs[32768];  // [64 rows][512B], swz bits4-6 by row&7
  {
    const char* hg = (const char*)(h + (size_t)hbase * Cc);
#pragma unroll
    for (int r = 0; r < 8; ++r) {
      int L = r * 4096 + threadIdx.x * 16;
      int lk = L ^ (((L >> 9) & 7) << 4);
      gload16(hg + lk, hs + L);
    }
  }
  __syncthreads();

  int lane = threadIdx.x & 63, wid = threadIdx.x >> 6;
  int lr = lane & 15, lg = lane >> 4;
  int sx = (lr & 7) << 4;

  // ---- Q and K: D[row=n 64][col=ch 128] = sum_c h[n][c] w[ch][c] + bias (xQSCALE for Q)
#pragma unroll
  for (int kind = 0; kind < 2; ++kind) {
    const unsigned short* w_ = wbf + (kind == 0 ? 0 : 65536);
    const float* bias = (kind == 0) ? bq : bk;
    float scale = (kind == 0) ? QSCALE : 1.f;
    unsigned char* O8 = (kind == 0 ? Q8g : K8g) + (size_t)bz * 262144;
    int colw = chh + wid * 32;   // wave's 32-ch slice
    f32x4 acc[4][2] = {};
    for (int k0 = 0; k0 < 256; k0 += 32) {
      bf16x8 a[4], bb[2];
#pragma unroll
      for (int i = 0; i < 4; ++i)
        a[i] = *reinterpret_cast<const bf16x8*>(
            hs + (((16 * i + lr) * 512 + k0 * 2 + lg * 16) ^ sx));
#pragma unroll
      for (int j = 0; j < 2; ++j)
        bb[j] = ldb8(w_ + (size_t)(colw + 16 * j + lr) * Cc + k0 + 8 * lg);
#pragma unroll
      for (int i = 0; i < 4; ++i)
#pragma unroll
        for (int j = 0; j < 2; ++j)
          acc[i][j] = __builtin_amdgcn_mfma_f32_16x16x32_bf16(a[i], bb[j], acc[i][j], 0, 0, 0);
    }
#pragma unroll
    for (int i = 0; i < 4; ++i)
#pragma unroll
      for (int j = 0; j < 2; ++j)
#pragma unroll
        for (int r = 0; r < 4; ++r) {
          int row = hbase + 16 * i + 4 * lg + r;  // n
          int col = colw + 16 * j + lr;           // ch
          float v = (acc[i][j][r] + bias[col]) * scale;
          int pk = __builtin_amdgcn_cvt_pk_fp8_f32(v, v, 0, false);
          size_t a8 = (size_t)(row >> 4) * 4096 + (size_t)(col >> 5) * 512 +
                      (size_t)((row & 15) + 16 * ((col >> 3) & 3)) * 8 + (col & 7);
          O8[a8] = (unsigned char)(pk & 0xff);
        }
  }

  // ---- V: D[row=ch 128][col=n 64] = sum_c wv[ch][c] h[n][c] + bv[ch]
  {
    const unsigned short* wv_ = wbf + 131072;
    unsigned char* O8 = V8g + (size_t)bz * 262144;
    int roww = chh + wid * 32;   // wave's 32-ch slice
    f32x4 acc[2][4] = {};
    for (int k0 = 0; k0 < 256; k0 += 32) {
      bf16x8 a[2], bb[4];
#pragma unroll
      for (int i = 0; i < 2; ++i)
        a[i] = ldb8(wv_ + (size_t)(roww + 16 * i + lr) * Cc + k0 + 8 * lg);
#pragma unroll
      for (int j = 0; j < 4; ++j)
        bb[j] = *reinterpret_cast<const bf16x8*>(
            hs + (((16 * j + lr) * 512 + k0 * 2 + lg * 16) ^ sx));
#pragma unroll
      for (int i = 0; i < 2; ++i)
#pragma unroll
        for (int j = 0; j < 4; ++j)
          acc[i][j] = __builtin_amdgcn_mfma_f32_16x16x32_bf16(a[i], bb[j], acc[i][j], 0, 0, 0);
    }
#pragma unroll
    for (int i = 0; i < 2; ++i)
#pragma unroll
      for (int j = 0; j < 4; ++j)
#pragma unroll
        for (int r = 0; r < 4; ++r) {
          int row = roww + 16 * i + 4 * lg + r;   // ch
          int col = hbase + 16 * j + lr;          // n/m
          float v = acc[i][j][r] + bv[row];
          int pk = __builtin_amdgcn_cvt_pk_fp8_f32(v, v, 0, false);
          size_t a8 = (size_t)(col >> 5) * 8192 + (size_t)(row >> 4) * 512 +
                      (size_t)((row & 15) + 16 * ((col >> 3) & 3)) * 8 + (col & 7);
          O8[a8] = (unsigned char)(pk & 0xff);
        }
  }
}

// ---------------- fused flash attention + out-proj + residual ----------------
// grid (BG, 16) batch-major; 256 thr = 4 waves; 64 q-cols/block.
// KVBLK=128 all-fp8, 8 iters x 2 barriers. V is NOT LDS-staged: K8/V8 are L2-resident
// (768KB/batch), and PV reads V as lane-linear coalesced b64 global loads. LDS holds
// only K (32KB) + P (8KB) + lsum -> 41KB -> 3 blocks/CU (12 waves/CU).
__global__ void __launch_bounds__(256, 3) attn_fused_kernel(
    const unsigned short* __restrict__ wbf, const float* __restrict__ bo,
    const unsigned char* __restrict__ Q8, const unsigned char* __restrict__ K8,
    const unsigned char* __restrict__ V8,
    const float* __restrict__ x, float* __restrict__ out) {
  int b = blockIdx.x;
  int tid = threadIdx.x;
  int lane = tid & 63, wid = tid >> 6;
  int lr = lane & 15, lg = lane >> 4;
  const char* Q8b = (const char*)(Q8 + (size_t)b * 262144) + blockIdx.y * 16384;
  const char* KTb = (const char*)(K8 + (size_t)b * 262144);
  const char* VTb = (const char*)(V8 + (size_t)b * 262144);
  const float* xb = x + (size_t)b * Cc * Nn;
  float* ob = out + (size_t)b * Cc * Nn;

  // LDS: [0,32K) K tile (128 n x 256 ch fp8, frag-linear)
  //      [32768,40960) P (fp8 frag-linear, [4 ks][4 cg][512B])
  //      [40960,41984) lsum partials [4 wid][4 qq][16 lr] f32
  //      epilogue reuses [0,32K) for hout bf16 [64 col][512B ch] (swizzled)
  __shared__ alignas(16) char lds[41984];

  auto stageK = [&](int t) {  // 32KB frag-linear in global -> pure linear copy
    const char* kg = KTb + (size_t)t * 32768;
#pragma unroll
    for (int r = 0; r < 8; ++r) {
      int Lb = r * 4096 + wid * 1024;
      gload16(kg + Lb + lane * 16, lds + Lb);
    }
  };

  stageK(0);

  // ---- Q fragments: direct loads from frag-linear Q8 (layout == K8, verified)
  long long q8a[4][8];
#pragma unroll
  for (int qq = 0; qq < 4; ++qq)
#pragma unroll
    for (int kk = 0; kk < 8; ++kk)
      q8a[qq][kk] = *reinterpret_cast<const long long*>(Q8b + qq * 4096 + kk * 512 + lane * 8);
  __syncthreads();  // K(0) staged (vmcnt drained at this barrier)

  f32x4 acc[4][4] = {};  // [cht][colt]: ch = wid*64+cht*16+4lg+r, col = colt*16+lr
  float lsum[4] = {0.f, 0.f, 0.f, 0.f};
  for (int t = 0; t < 8; ++t) {
    // ---- QK^T (fp8): this wave's 32-row quarter x ALL 64 cols
    f32x4 st[2][4] = {};
    __builtin_amdgcn_s_setprio(1);
#pragma unroll
    for (int kk = 0; kk < 8; ++kk) {
      long long kf0 = *reinterpret_cast<const long long*>(lds + (wid * 2) * 4096 + kk * 512 + lane * 8);
      long long kf1 = *reinterpret_cast<const long long*>(lds + (wid * 2 + 1) * 4096 + kk * 512 + lane * 8);
#pragma unroll
      for (int qq = 0; qq < 4; ++qq) {
        st[0][qq] = __builtin_amdgcn_mfma_f32_16x16x32_fp8_fp8(kf0, q8a[qq][kk], st[0][qq], 0, 0, 0);
        st[1][qq] = __builtin_amdgcn_mfma_f32_16x16x32_fp8_fp8(kf1, q8a[qq][kk], st[1][qq], 0, 0, 0);
      }
    }
    __builtin_amdgcn_s_setprio(0);
    // p = exp2(s) (fixed max 0); publish fp8 P: m = (2wid+g2)*16+4lg+r, col = qq*16+lr
#pragma unroll
    for (int g2 = 0; g2 < 2; ++g2) {
      char* pwb = lds + 32768 + wid * 2048 + (lr + 16 * (2 * g2 + (lg >> 1))) * 8 + 4 * (lg & 1);
#pragma unroll
      for (int qq = 0; qq < 4; ++qq) {
        float p0 = fexp2(st[g2][qq][0]), p1 = fexp2(st[g2][qq][1]);
        float p2 = fexp2(st[g2][qq][2]), p3 = fexp2(st[g2][qq][3]);
        lsum[qq] += (p0 + p1) + (p2 + p3);
        int u = __builtin_amdgcn_cvt_pk_fp8_f32(p0, p1, 0, false);
        u = __builtin_amdgcn_cvt_pk_fp8_f32(p2, p3, u, true);
        *reinterpret_cast<int*>(pwb + qq * 512) = u;
      }
    }
    __syncthreads();  // A: P visible, all K reads done
    if (t < 7) stageK(t + 1);  // overwrites K buf (safe: QK done block-wide)
    // ---- channel-split PV (fp8): P from LDS, V direct from L2 (frag-linear, coalesced)
    const char* vt = VTb + (size_t)t * 32768;
#pragma unroll
    for (int ks = 0; ks < 4; ++ks) {
      long long Pf[4], Vf[4];
#pragma unroll
      for (int ct = 0; ct < 4; ++ct)
        Pf[ct] = *reinterpret_cast<const long long*>(lds + 32768 + ks * 2048 + ct * 512 + lane * 8);
#pragma unroll
      for (int ch = 0; ch < 4; ++ch)
        Vf[ch] = *reinterpret_cast<const long long*>(vt + ks * 8192 + (wid * 4 + ch) * 512 + lane * 8);
      __builtin_amdgcn_s_setprio(1);
#pragma unroll
      for (int ch = 0; ch < 4; ++ch)
#pragma unroll
        for (int ct = 0; ct < 4; ++ct)
          acc[ch][ct] = __builtin_amdgcn_mfma_f32_16x16x32_fp8_fp8(Vf[ch], Pf[ct], acc[ch][ct], 0, 0, 0);
      __builtin_amdgcn_s_setprio(0);
    }
    __syncthreads();  // B: K(t+1) staged, all P reads done
  }
  // finalize denominators
#pragma unroll
  for (int qq = 0; qq < 4; ++qq) {
    lsum[qq] += __shfl_xor(lsum[qq], 16, 64);
    lsum[qq] += __shfl_xor(lsum[qq], 32, 64);
  }
  if (lg == 0) {
#pragma unroll
    for (int qq = 0; qq < 4; ++qq)
      *reinterpret_cast<float*>(lds + 40960 + ((wid * 4 + qq) * 16 + lr) * 4) = lsum[qq];
  }
  __syncthreads();
  float inv[4];
#pragma unroll
  for (int ct = 0; ct < 4; ++ct) {
    float s = 0.f;
#pragma unroll
    for (int w = 0; w < 4; ++w)
      s += *reinterpret_cast<const float*>(lds + 40960 + ((w * 4 + ct) * 16 + lr) * 4);
    inv[ct] = 1.f / s;
  }

  // ---- exchange hout via LDS: bf16 [64 col][256 ch], 512B rows, swizzle ^((col&7)<<4)
#pragma unroll
  for (int ch = 0; ch < 4; ++ch)
#pragma unroll
    for (int ct = 0; ct < 4; ++ct) {
      float h0 = acc[ch][ct][0] * inv[ct], h1 = acc[ch][ct][1] * inv[ct];
      float h2 = acc[ch][ct][2] * inv[ct], h3 = acc[ch][ct][3] * inv[ct];
      unsigned w0, w1;
      asm("v_cvt_pk_bf16_f32 %0, %1, %2" : "=v"(w0) : "v"(h0), "v"(h1));
      asm("v_cvt_pk_bf16_f32 %0, %1, %2" : "=v"(w1) : "v"(h2), "v"(h3));
      int col = ct * 16 + lr;
      int chb = wid * 128 + ch * 32 + 8 * lg;
      int off = (col * 512 + chb) ^ ((col & 7) << 4);
      *reinterpret_cast<uint2*>(lds + off) = make_uint2(w0, w1);
    }
  __syncthreads();

  // ---- ch-split out-projection + bias + residual: wave w -> o rows [64w,64w+64)
  const unsigned short* wob = wbf + 196608;
  int nbase = blockIdx.y * 64;
#pragma unroll
  for (int t2 = 0; t2 < 4; ++t2) {
    int orow = 64 * wid + 16 * t2;
    bf16x8 wf[8];
#pragma unroll
    for (int kk = 0; kk < 8; ++kk)
      wf[kk] = ldb8(wob + (size_t)(orow + lr) * Cc + 32 * kk + 8 * lg);
    float4 bov = *reinterpret_cast<const float4*>(bo + orow + 4 * lg);
#pragma unroll
    for (int qq = 0; qq < 4; ++qq) {
      f32x4 ao = {0.f, 0.f, 0.f, 0.f};
#pragma unroll
      for (int kk = 0; kk < 8; ++kk) {
        int off = ((qq * 16 + lr) * 512 + 64 * kk + 16 * lg) ^ ((lr & 7) << 4);
        bf16x8 hb = *reinterpret_cast<const bf16x8*>(lds + off);
        ao = __builtin_amdgcn_mfma_f32_16x16x32_bf16(wf[kk], hb, ao, 0, 0, 0);
      }
#pragma unroll
      for (int r = 0; r < 4; ++r) {
        int o = orow + 4 * lg + r;
        size_t idx = (size_t)o * Nn + nbase + qq * 16 + lr;
        ob[idx] = xb[idx] + ((const float*)&bov)[r] + ao[r];
      }
    }
  }
}

extern "C" void kernel_launch(void* const* d_in, const int* in_sizes, int n_in,
                              void* d_out, int out_size, void* d_ws, size_t ws_size,
                              hipStream_t stream) {
  const float* x  = (const float*)d_in[0];
  const float* gw = (const float*)d_in[1];
  const float* gb = (const float*)d_in[2];
  const float* wq = (const float*)d_in[3];
  const float* bq = (const float*)d_in[4];
  const float* wk = (const float*)d_in[5];
  const float* bk = (const float*)d_in[6];
  const float* wv = (const float*)d_in[7];
  const float* bv = (const float*)d_in[8];
  const float* wo = (const float*)d_in[9];
  const float* bo = (const float*)d_in[10];
  float* out = (float*)d_out;
  char* ws = (char*)d_ws;

  // workspace layout — NEVER exceed ws_size:
  //   [0, 512KB)   wbf: 4 weight matrices bf16
  //   [1MB, 17MB)  hT [B,N,C] bf16
  //   [17MB, ...)  Q8 + K8 + V8 fp8 frag (3 x 256KB/batch) for BG batches
  unsigned short* wbf = (unsigned short*)ws;
  unsigned short* hT  = (unsigned short*)(ws + (1 << 20));
  const size_t KV_OFF = (size_t)17 << 20;
  const size_t perBatchKV = 3 * 262144;  // 768KB
  size_t avail = ws_size > KV_OFF ? ws_size - KV_OFF : 0;
  int BG = 32;
  while (BG > 1 && (size_t)BG * perBatchKV > avail) BG >>= 1;

  gn_cvt_kernel<<<dim3(1280), dim3(256), 0, stream>>>(x, gw, gb, hT, wq, wk, wv, wo, wbf);

  unsigned char* Q8g = (unsigned char*)(ws + KV_OFF);
  unsigned char* K8g = Q8g + (size_t)BG * 262144;
  unsigned char* V8g = K8g + (size_t)BG * 262144;

  for (int g = 0; g < Bb; g += BG) {
    unsigned short* hTg = hT + (size_t)g * Nn * Cc;
    qkv_gemm_kernel<<<dim3(32, BG), dim3(256), 0, stream>>>(
        hTg, wbf, Q8g, K8g, V8g, bq, bk, bv);
    attn_fused_kernel<<<dim3(BG, 16), dim3(256), 0, stream>>>(
        wbf, bo, Q8g, K8g, V8g, x + (size_t)g * Cc * Nn, out + (size_t)g * Cc * Nn);
  }
}